// Round 3
// baseline (4288.982 us; speedup 1.0000x reference)
//
#include <hip/hip_runtime.h>
#include <hip/hip_bf16.h>
#include <cstdint>

#define M_DIM 4096
#define K_DIM 4096
#define N_DIM 11008
#define NT_K  (K_DIM / 64)          // 64 K-tiles of BK=64

typedef __attribute__((ext_vector_type(8))) short short8;
typedef __attribute__((ext_vector_type(4))) float floatx4;

__device__ __forceinline__ unsigned short f2bf(float f) {
    union { float f; unsigned u; } v; v.f = f;
    unsigned r = v.u + 0x7FFFu + ((v.u >> 16) & 1u);   // round-to-nearest-even
    return (unsigned short)(r >> 16);
}

__device__ __forceinline__ void async_copy16(const ushort* g, const ushort* l) {
    __builtin_amdgcn_global_load_lds(
        (const __attribute__((address_space(1))) void*)(uintptr_t)(const void*)g,
        (__attribute__((address_space(3))) void*)(uintptr_t)(const void*)l,
        16, 0, 0);
}

// ---------------------------------------------------------------------------
// Fused prep.
//  blocks [0, M_DIM):        x fp32->bf16 + row sums.
//  blocks [M_DIM, +688*8):   weight int32->bf16, written PACKED in MFMA
//    B-fragment order: element (n,k) ->
//      wb[ ((n>>4)*128 + (k>>5))*512 + ((k>>3)&3)*128 + (n&15)*8 + (k&7) ]
//    so one 16x32 (n x k) sub-block = 64 lanes x 16B contiguous, and the GEMM
//    loads each B fragment as a single coalesced global_load_dwordx4 per lane.
// ---------------------------------------------------------------------------
__global__ void prep_kernel(const float* __restrict__ x, const int* __restrict__ w,
                            ushort* __restrict__ xb, ushort* __restrict__ wb,
                            float* __restrict__ s) {
    const int tid = threadIdx.x;                 // 256 threads
    if (blockIdx.x < M_DIM) {
        const int row = blockIdx.x;
        const float*  xr = x  + (size_t)row * K_DIM;
        ushort*       xo = xb + (size_t)row * K_DIM;
        float sum = 0.f;
#pragma unroll
        for (int i = 0; i < 2; ++i) {
            int e = (tid + i * 256) * 8;         // 8 floats per unit
            float4 v0 = *(const float4*)(xr + e);
            float4 v1 = *(const float4*)(xr + e + 4);
            sum += v0.x + v0.y + v0.z + v0.w + v1.x + v1.y + v1.z + v1.w;
            short8 o;
            o[0] = f2bf(v0.x); o[1] = f2bf(v0.y); o[2] = f2bf(v0.z); o[3] = f2bf(v0.w);
            o[4] = f2bf(v1.x); o[5] = f2bf(v1.y); o[6] = f2bf(v1.z); o[7] = f2bf(v1.w);
            *(short8*)(xo + e) = o;
        }
#pragma unroll
        for (int off = 32; off > 0; off >>= 1) sum += __shfl_down(sum, off, 64);
        __shared__ float red[4];
        if ((tid & 63) == 0) red[tid >> 6] = sum;
        __syncthreads();
        if (tid == 0) s[row] = red[0] + red[1] + red[2] + red[3];
    } else {
        // Block (nb, kg): 16 n-rows x 512 k. Thread (n_i, kq): 32 k of one row.
        const int p   = blockIdx.x - M_DIM;      // 0..5503
        const int nb  = p >> 3;                  // 0..687
        const int kg  = p & 7;                   // 0..7
        const int n_i = tid >> 4;                // 0..15
        const int kq  = tid & 15;                // 0..15
        const int* in = w + (size_t)(nb * 16 + n_i) * K_DIM + kg * 512 + kq * 32;
        int4 v[8];
#pragma unroll
        for (int i = 0; i < 8; ++i) v[i] = ((const int4*)in)[i];
        ushort* out = wb + ((size_t)nb * 128 + kg * 16 + kq) * 512 + n_i * 8;
#pragma unroll
        for (int q = 0; q < 4; ++q) {
            int4 v0 = v[2 * q], v1 = v[2 * q + 1];
            short8 o;
            o[0] = f2bf((float)v0.x); o[1] = f2bf((float)v0.y);
            o[2] = f2bf((float)v0.z); o[3] = f2bf((float)v0.w);
            o[4] = f2bf((float)v1.x); o[5] = f2bf((float)v1.y);
            o[6] = f2bf((float)v1.z); o[7] = f2bf((float)v1.w);
            *(short8*)(out + q * 128) = o;
        }
    }
}

// ---------------------------------------------------------------------------
// 256x256 tile, BK=64, 8 waves (2M x 4N), 4 phases/K-tile.
// A: LDS double-buffered (64 KiB total -> 2 blocks/CU).  B: direct global->reg
// from the packed layout, double-buffered one tile ahead (each B fragment read
// by 2 waves; skips B's LDS write+read -> LDS traffic 256->160 KB/tile < MFMA
// floor).  vmcnt(4) per tile keeps B(t+1) loads in flight across the barrier.
// ---------------------------------------------------------------------------

#define BAR()                                   \
    __builtin_amdgcn_sched_barrier(0);          \
    __builtin_amdgcn_s_barrier();               \
    __builtin_amdgcn_sched_barrier(0)

#define LDA(dst, base, q)                                                     \
    _Pragma("unroll")                                                         \
    for (int fl = 0; fl < 2; ++fl)                                            \
        _Pragma("unroll")                                                     \
        for (int ks = 0; ks < 2; ++ks)                                        \
            dst[fl][ks] = *(const short8*)((const ushort*)(base) + aoff[ks] + (q) * 2048 + fl * 1024)

// Load B fragments fn0_, fn0_+1 (ks=0,1) of k-block kb straight to registers.
#define GLBP(dst, fn0_, kb)                                                   \
    _Pragma("unroll")                                                         \
    for (int f = 0; f < 2; ++f)                                               \
        _Pragma("unroll")                                                     \
        for (int ks = 0; ks < 2; ++ks)                                        \
            dst[(fn0_) + f][ks] = *(const short8*)(bBase + ((size_t)((fn0_) + f) * 128 + (kb) + ks) * 512)

#define MFMAQ(ar, bc, q)                                                      \
    __builtin_amdgcn_s_setprio(1);                                            \
    _Pragma("unroll")                                                         \
    for (int fl = 0; fl < 2; ++fl)                                            \
        _Pragma("unroll")                                                     \
        for (int fn = 0; fn < 4; ++fn)                                        \
            _Pragma("unroll")                                                 \
            for (int ks = 0; ks < 2; ++ks)                                    \
                acc[(q) * 2 + fl][fn] = __builtin_amdgcn_mfma_f32_16x16x32_bf16( \
                    ar[fl][ks], bc[fn][ks], acc[(q) * 2 + fl][fn], 0, 0, 0);  \
    __builtin_amdgcn_s_setprio(0)

// One K-tile t. KA = k-offset of A(t+1) stage; KBN = k-block of B(t+1) loads.
// AR/AW: A read/write LDS slots. BC: B(t) regs (consumed); BN: B(t+1) regs.
#define TILE(KA, KBN, AR, AW, BC, BN)                                         \
    /* ph0 */                                                                 \
    BAR();                                                                    \
    async_copy16(aSrc + (KA),                       (AW) + sdst);             \
    LDA(a1, AR, 1);                                                           \
    MFMAQ(a0, BC, 0);                                                         \
    /* ph1 */                                                                 \
    BAR();                                                                    \
    async_copy16(aSrc + (size_t) 64 * K_DIM + (KA), (AW) + sdst + 4096);      \
    LDA(a0, AR, 2);                                                           \
    MFMAQ(a1, BC, 1);                                                         \
    /* ph2 */                                                                 \
    BAR();                                                                    \
    async_copy16(aSrc + (size_t)128 * K_DIM + (KA), (AW) + sdst + 8192);      \
    GLBP(BN, 0, KBN);                                                         \
    LDA(a1, AR, 3);                                                           \
    MFMAQ(a0, BC, 2);                                                         \
    /* ph3: last A stage must be OLDER than the last 4 B loads -> vmcnt(4)  */ \
    async_copy16(aSrc + (size_t)192 * K_DIM + (KA), (AW) + sdst + 12288);     \
    __builtin_amdgcn_sched_barrier(0);                                        \
    GLBP(BN, 2, KBN);                                                         \
    asm volatile("s_waitcnt vmcnt(4)" ::: "memory");                          \
    BAR();                                                                    \
    LDA(a0, AW, 0);                                                           \
    MFMAQ(a1, BC, 3)

__global__ __launch_bounds__(512, 4) void gemm_kernel(
        const ushort* __restrict__ xb, const ushort* __restrict__ wbp,
        const float* __restrict__ s, const float* __restrict__ scale,
        const float* __restrict__ offset, const float* __restrict__ bias,
        float* __restrict__ y) {
    __shared__ ushort lds[2][256 * 64];        // A only: 64 KiB -> 2 blocks/CU

    const int tid  = threadIdx.x;
    const int lane = tid & 63;
    const int wave = tid >> 6;          // 0..7
    const int wm   = wave >> 2;         // 0..1  (M half)
    const int wn   = wave & 3;          // 0..3  (N quarter)
    const int r15  = lane & 15;
    const int quad = lane >> 4;

    // XCD-aware bijective swizzle: 688 blocks = 8 XCDs x 86 contiguous ids.
    const int wg  = blockIdx.x;
    const int swzid = (wg & 7) * 86 + (wg >> 3);
    const int m0  = (swzid & 15) * 256;
    const int n0  = (swzid >> 4) * 256;

    // --- A staging (linear LDS dest, chunk-XOR pre-swizzled global source) ---
    const int    srow = wave * 8 + (lane >> 3);
    const int    scol = ((lane & 7) ^ (lane >> 3)) * 8;
    const ushort* aSrc = xb + (size_t)(m0 + srow) * K_DIM + scol;
    const int    sdst = wave * 512;            // element offset (+ l*4096)

    // --- A read offsets: chunk (ks*4+quad) ^ (row&7) ---
    const int x7 = r15 & 7;
    int aoff[2];
#pragma unroll
    for (int ks = 0; ks < 2; ++ks)
        aoff[ks] = (wm * 128 + r15) * 64 + ((ks * 4 + quad) ^ x7) * 8;

    // --- B: packed-fragment base; each fragment = coalesced lane*16B load ---
    const ushort* bBase = wbp + (size_t)((n0 >> 4) + wn * 4) * 128 * 512
                              + (size_t)lane * 8;

    const ushort* lds0A = &lds[0][0];
    const ushort* lds1A = &lds[1][0];

    floatx4 acc[8][4] = {};
    short8 a0[2][2], a1[2][2], b0[4][2], b1[4][2];

    // --- prologue: stage A(0)->slot0 (4 oldest), load B(0)->b0 (8 youngest),
    //     vmcnt(8) -> A(0) visible; B(0) regs auto-waited at first use. ---
#pragma unroll
    for (int l = 0; l < 4; ++l)
        async_copy16(aSrc + (size_t)l * 64 * K_DIM, lds0A + sdst + l * 4096);
    __builtin_amdgcn_sched_barrier(0);
    GLBP(b0, 0, 0);
    GLBP(b0, 2, 0);
    asm volatile("s_waitcnt vmcnt(8)" ::: "memory");
    __builtin_amdgcn_s_barrier();
    LDA(a0, lds0A, 0);

    for (int t = 0; t < NT_K; t += 2) {
        // even tile t: read slot0, stage A(t+1)->slot1, load B(t+1)->b1
        const size_t ka0 = (size_t)(t + 1) * 64;     // t+1 <= 63, in range
        const int    kb0 = 2 * (t + 1);
        TILE(ka0, kb0, lds0A, lds1A, b0, b1);
        // odd tile t+1: mirrored
        const size_t ka1 = (t + 2 < NT_K) ? (size_t)(t + 2) * 64 : 0;  // clamped,
        const int    kb1 = (t + 2 < NT_K) ? 2 * (t + 2) : 0;           // never read
        TILE(ka1, kb1, lds1A, lds0A, b1, b0);
    }

    // ---- epilogue: y = scale*(acc + off*rowsum) + bias ----
    float sm[8][4];
#pragma unroll
    for (int fm = 0; fm < 8; ++fm)
#pragma unroll
        for (int r = 0; r < 4; ++r)
            sm[fm][r] = s[m0 + wm * 128 + fm * 16 + quad * 4 + r];

#pragma unroll
    for (int fn = 0; fn < 4; ++fn) {
        const int n = n0 + wn * 64 + fn * 16 + r15;
        const float sc = scale[n], of = offset[n], bi = bias[n];
#pragma unroll
        for (int fm = 0; fm < 8; ++fm) {
            const int mb = m0 + wm * 128 + fm * 16 + quad * 4;
#pragma unroll
            for (int r = 0; r < 4; ++r) {
                y[(size_t)(mb + r) * N_DIM + n] =
                    sc * (acc[fm][fn][r] + of * sm[fm][r]) + bi;
            }
        }
    }
}

extern "C" void kernel_launch(void* const* d_in, const int* in_sizes, int n_in,
                              void* d_out, int out_size, void* d_ws, size_t ws_size,
                              hipStream_t stream) {
    const float* x      = (const float*)d_in[0];
    const int*   weight = (const int*)d_in[1];
    const float* scale  = (const float*)d_in[2];
    const float* offset = (const float*)d_in[3];
    const float* bias   = (const float*)d_in[4];
    float*       y      = (float*)d_out;

    // Workspace layout (bytes): xb bf16 M*K | wb packed bf16 N*K | s fp32 M
    ushort* xb = (ushort*)d_ws;
    ushort* wb = (ushort*)((char*)d_ws + (size_t)M_DIM * K_DIM * 2);
    float*  s  = (float*)((char*)d_ws + (size_t)M_DIM * K_DIM * 2 + (size_t)N_DIM * K_DIM * 2);

    // x rows (4096 blocks) + packed-w blocks (688 nblk x 8 kgroups = 5504)
    prep_kernel<<<M_DIM + 688 * 8, 256, 0, stream>>>(x, weight, xb, wb, s);

    gemm_kernel<<<dim3((N_DIM / 256) * (M_DIM / 256)), dim3(512), 0, stream>>>(
        xb, wb, s, scale, offset, bias, y);
}

// Round 4
// 815.526 us; speedup vs baseline: 5.2592x; 5.2592x over previous
//
#include <hip/hip_runtime.h>
#include <hip/hip_bf16.h>
#include <cstdint>

#define M_DIM 4096
#define K_DIM 4096
#define N_DIM 11008
#define NT_K  (K_DIM / 64)          // 64 K-tiles of BK=64

typedef __attribute__((ext_vector_type(8))) short short8;
typedef __attribute__((ext_vector_type(4))) float floatx4;

__device__ __forceinline__ unsigned short f2bf(float f) {
    union { float f; unsigned u; } v; v.f = f;
    unsigned r = v.u + 0x7FFFu + ((v.u >> 16) & 1u);   // round-to-nearest-even
    return (unsigned short)(r >> 16);
}

__device__ __forceinline__ void async_copy16(const ushort* g, const ushort* l) {
    __builtin_amdgcn_global_load_lds(
        (const __attribute__((address_space(1))) void*)(uintptr_t)(const void*)g,
        (__attribute__((address_space(3))) void*)(uintptr_t)(const void*)l,
        16, 0, 0);
}

// ---------------------------------------------------------------------------
// Fused prep.
//  blocks [0, M_DIM):        x fp32->bf16 + row sums.
//  blocks [M_DIM, +688*8):   weight int32->bf16, PACKED in MFMA B-fragment
//    order: element (n,k) ->
//      wb[ ((n>>4)*128 + (k>>5))*512 + ((k>>3)&3)*128 + (n&15)*8 + (k&7) ]
//    Routed through LDS so BOTH the global read (128B/lane) and the global
//    write (lane-contiguous 1KB chunks) are fully coalesced.
// ---------------------------------------------------------------------------
__global__ void prep_kernel(const float* __restrict__ x, const int* __restrict__ w,
                            ushort* __restrict__ xb, ushort* __restrict__ wb,
                            float* __restrict__ s) {
    const int tid = threadIdx.x;                 // 256 threads
    if (blockIdx.x < M_DIM) {
        const int row = blockIdx.x;
        const float*  xr = x  + (size_t)row * K_DIM;
        ushort*       xo = xb + (size_t)row * K_DIM;
        float sum = 0.f;
#pragma unroll
        for (int i = 0; i < 2; ++i) {
            int e = (tid + i * 256) * 8;         // 8 floats per unit
            float4 v0 = *(const float4*)(xr + e);
            float4 v1 = *(const float4*)(xr + e + 4);
            sum += v0.x + v0.y + v0.z + v0.w + v1.x + v1.y + v1.z + v1.w;
            short8 o;
            o[0] = f2bf(v0.x); o[1] = f2bf(v0.y); o[2] = f2bf(v0.z); o[3] = f2bf(v0.w);
            o[4] = f2bf(v1.x); o[5] = f2bf(v1.y); o[6] = f2bf(v1.z); o[7] = f2bf(v1.w);
            *(short8*)(xo + e) = o;
        }
#pragma unroll
        for (int off = 32; off > 0; off >>= 1) sum += __shfl_down(sum, off, 64);
        __shared__ float red[4];
        if ((tid & 63) == 0) red[tid >> 6] = sum;
        __syncthreads();
        if (tid == 0) s[row] = red[0] + red[1] + red[2] + red[3];
    } else {
        // Block (nb, kg): 16 n-rows x 512 k.
        __shared__ ushort l[16][536];            // row pad -> spread banks
        const int p   = blockIdx.x - M_DIM;      // 0..5503
        const int nb  = p >> 3;                  // 0..687
        const int kg  = p & 7;                   // 0..7
        // read phase: n_i = tid>>4, kq = tid&15 -> coalesced 2KB per 16 lanes
        {
            const int n_i = tid >> 4;
            const int kq  = tid & 15;
            const int* in = w + (size_t)(nb * 16 + n_i) * K_DIM + kg * 512 + kq * 32;
#pragma unroll
            for (int q = 0; q < 4; ++q) {
                int4 v0 = ((const int4*)in)[2 * q];
                int4 v1 = ((const int4*)in)[2 * q + 1];
                short8 o;
                o[0] = f2bf((float)v0.x); o[1] = f2bf((float)v0.y);
                o[2] = f2bf((float)v0.z); o[3] = f2bf((float)v0.w);
                o[4] = f2bf((float)v1.x); o[5] = f2bf((float)v1.y);
                o[6] = f2bf((float)v1.z); o[7] = f2bf((float)v1.w);
                *(short8*)&l[n_i][kq * 32 + q * 8] = o;
            }
        }
        __syncthreads();
        // write phase: chunk c = wave*4+q2; lane lam writes pos lam*8 of chunk
        // -> each store instruction covers a contiguous 1KB chunk per wave.
        {
            const int lam = tid & 63;
            const int wv  = tid >> 6;            // 0..3
            ushort* outb = wb + ((size_t)nb * 128 + kg * 16) * 512;
#pragma unroll
            for (int q2 = 0; q2 < 4; ++q2) {
                const int c = wv * 4 + q2;       // k-chunk 0..15
                short8 v8 = *(const short8*)&l[lam & 15][c * 32 + (lam >> 4) * 8];
                *(short8*)(outb + (size_t)c * 512 + lam * 8) = v8;
            }
        }
    }
}

// ---------------------------------------------------------------------------
// 256x256 tile, BK=64, 8 waves (2M x 4N), 4 phases/K-tile.
// A: LDS double-buffered (64 KiB). B: direct global->reg from packed layout,
// double-buffered one tile ahead. LDS traffic 160 KB/tile < MFMA floor.
// __launch_bounds__(512, 2): 256-reg unified budget = 128 AGPR acc + <=128
// arch. (512,4) forced a 128 budget and spilled acc to scratch: 10.9 GB
// writes, 6x slowdown. Do NOT raise the min-waves arg on this tile shape.
// ---------------------------------------------------------------------------

#define BAR()                                   \
    __builtin_amdgcn_sched_barrier(0);          \
    __builtin_amdgcn_s_barrier();               \
    __builtin_amdgcn_sched_barrier(0)

#define LDA(dst, base, q)                                                     \
    _Pragma("unroll")                                                         \
    for (int fl = 0; fl < 2; ++fl)                                            \
        _Pragma("unroll")                                                     \
        for (int ks = 0; ks < 2; ++ks)                                        \
            dst[fl][ks] = *(const short8*)((const ushort*)(base) + aoff[ks] + (q) * 2048 + fl * 1024)

// Load B fragments fn0_, fn0_+1 (ks=0,1) of k-block kb straight to registers.
#define GLBP(dst, fn0_, kb)                                                   \
    _Pragma("unroll")                                                         \
    for (int f = 0; f < 2; ++f)                                               \
        _Pragma("unroll")                                                     \
        for (int ks = 0; ks < 2; ++ks)                                        \
            dst[(fn0_) + f][ks] = *(const short8*)(bBase + ((size_t)((fn0_) + f) * 128 + (kb) + ks) * 512)

#define MFMAQ(ar, bc, q)                                                      \
    __builtin_amdgcn_s_setprio(1);                                            \
    _Pragma("unroll")                                                         \
    for (int fl = 0; fl < 2; ++fl)                                            \
        _Pragma("unroll")                                                     \
        for (int fn = 0; fn < 4; ++fn)                                        \
            _Pragma("unroll")                                                 \
            for (int ks = 0; ks < 2; ++ks)                                    \
                acc[(q) * 2 + fl][fn] = __builtin_amdgcn_mfma_f32_16x16x32_bf16( \
                    ar[fl][ks], bc[fn][ks], acc[(q) * 2 + fl][fn], 0, 0, 0);  \
    __builtin_amdgcn_s_setprio(0)

// One K-tile t. KA = k-offset of A(t+1) stage; KBN = k-block of B(t+1) loads.
#define TILE(KA, KBN, AR, AW, BC, BN)                                         \
    /* ph0 */                                                                 \
    BAR();                                                                    \
    async_copy16(aSrc + (KA),                       (AW) + sdst);             \
    LDA(a1, AR, 1);                                                           \
    MFMAQ(a0, BC, 0);                                                         \
    /* ph1 */                                                                 \
    BAR();                                                                    \
    async_copy16(aSrc + (size_t) 64 * K_DIM + (KA), (AW) + sdst + 4096);      \
    LDA(a0, AR, 2);                                                           \
    MFMAQ(a1, BC, 1);                                                         \
    /* ph2 */                                                                 \
    BAR();                                                                    \
    async_copy16(aSrc + (size_t)128 * K_DIM + (KA), (AW) + sdst + 8192);      \
    GLBP(BN, 0, KBN);                                                         \
    LDA(a1, AR, 3);                                                           \
    MFMAQ(a0, BC, 2);                                                         \
    /* ph3: last A stage must be OLDER than the last 4 B loads -> vmcnt(4)  */ \
    async_copy16(aSrc + (size_t)192 * K_DIM + (KA), (AW) + sdst + 12288);     \
    __builtin_amdgcn_sched_barrier(0);                                        \
    GLBP(BN, 2, KBN);                                                         \
    asm volatile("s_waitcnt vmcnt(4)" ::: "memory");                          \
    BAR();                                                                    \
    LDA(a0, AW, 0);                                                           \
    MFMAQ(a1, BC, 3)

__global__ __launch_bounds__(512, 2) void gemm_kernel(
        const ushort* __restrict__ xb, const ushort* __restrict__ wbp,
        const float* __restrict__ s, const float* __restrict__ scale,
        const float* __restrict__ offset, const float* __restrict__ bias,
        float* __restrict__ y) {
    __shared__ ushort lds[2][256 * 64];        // A only: 64 KiB

    const int tid  = threadIdx.x;
    const int lane = tid & 63;
    const int wave = tid >> 6;          // 0..7
    const int wm   = wave >> 2;         // 0..1  (M half)
    const int wn   = wave & 3;          // 0..3  (N quarter)
    const int r15  = lane & 15;
    const int quad = lane >> 4;

    // XCD-aware bijective swizzle: 688 blocks = 8 XCDs x 86 contiguous ids.
    const int wg  = blockIdx.x;
    const int swzid = (wg & 7) * 86 + (wg >> 3);
    const int m0  = (swzid & 15) * 256;
    const int n0  = (swzid >> 4) * 256;

    // --- A staging (linear LDS dest, chunk-XOR pre-swizzled global source) ---
    const int    srow = wave * 8 + (lane >> 3);
    const int    scol = ((lane & 7) ^ (lane >> 3)) * 8;
    const ushort* aSrc = xb + (size_t)(m0 + srow) * K_DIM + scol;
    const int    sdst = wave * 512;            // element offset (+ l*4096)

    // --- A read offsets: chunk (ks*4+quad) ^ (row&7) ---
    const int x7 = r15 & 7;
    int aoff[2];
#pragma unroll
    for (int ks = 0; ks < 2; ++ks)
        aoff[ks] = (wm * 128 + r15) * 64 + ((ks * 4 + quad) ^ x7) * 8;

    // --- B: packed-fragment base; each fragment = coalesced lane*16B load ---
    const ushort* bBase = wbp + (size_t)((n0 >> 4) + wn * 4) * 128 * 512
                              + (size_t)lane * 8;

    const ushort* lds0A = &lds[0][0];
    const ushort* lds1A = &lds[1][0];

    floatx4 acc[8][4] = {};
    short8 a0[2][2], a1[2][2], b0[4][2], b1[4][2];

    // --- prologue: stage A(0)->slot0 (4 oldest), load B(0)->b0 (8 youngest),
    //     vmcnt(8) -> A(0) visible; B(0) regs auto-waited at first use. ---
#pragma unroll
    for (int l = 0; l < 4; ++l)
        async_copy16(aSrc + (size_t)l * 64 * K_DIM, lds0A + sdst + l * 4096);
    __builtin_amdgcn_sched_barrier(0);
    GLBP(b0, 0, 0);
    GLBP(b0, 2, 0);
    asm volatile("s_waitcnt vmcnt(8)" ::: "memory");
    __builtin_amdgcn_s_barrier();
    LDA(a0, lds0A, 0);

    for (int t = 0; t < NT_K; t += 2) {
        // even tile t: read slot0, stage A(t+1)->slot1, load B(t+1)->b1
        const size_t ka0 = (size_t)(t + 1) * 64;     // t+1 <= 63, in range
        const int    kb0 = 2 * (t + 1);
        TILE(ka0, kb0, lds0A, lds1A, b0, b1);
        // odd tile t+1: mirrored
        const size_t ka1 = (t + 2 < NT_K) ? (size_t)(t + 2) * 64 : 0;  // clamped,
        const int    kb1 = (t + 2 < NT_K) ? 2 * (t + 2) : 0;           // never read
        TILE(ka1, kb1, lds1A, lds0A, b1, b0);
    }

    // ---- epilogue: y = scale*(acc + off*rowsum) + bias ----
    float sm[8][4];
#pragma unroll
    for (int fm = 0; fm < 8; ++fm)
#pragma unroll
        for (int r = 0; r < 4; ++r)
            sm[fm][r] = s[m0 + wm * 128 + fm * 16 + quad * 4 + r];

#pragma unroll
    for (int fn = 0; fn < 4; ++fn) {
        const int n = n0 + wn * 64 + fn * 16 + r15;
        const float sc = scale[n], of = offset[n], bi = bias[n];
#pragma unroll
        for (int fm = 0; fm < 8; ++fm) {
            const int mb = m0 + wm * 128 + fm * 16 + quad * 4;
#pragma unroll
            for (int r = 0; r < 4; ++r) {
                y[(size_t)(mb + r) * N_DIM + n] =
                    sc * (acc[fm][fn][r] + of * sm[fm][r]) + bi;
            }
        }
    }
}

extern "C" void kernel_launch(void* const* d_in, const int* in_sizes, int n_in,
                              void* d_out, int out_size, void* d_ws, size_t ws_size,
                              hipStream_t stream) {
    const float* x      = (const float*)d_in[0];
    const int*   weight = (const int*)d_in[1];
    const float* scale  = (const float*)d_in[2];
    const float* offset = (const float*)d_in[3];
    const float* bias   = (const float*)d_in[4];
    float*       y      = (float*)d_out;

    // Workspace layout (bytes): xb bf16 M*K | wb packed bf16 N*K | s fp32 M
    ushort* xb = (ushort*)d_ws;
    ushort* wb = (ushort*)((char*)d_ws + (size_t)M_DIM * K_DIM * 2);
    float*  s  = (float*)((char*)d_ws + (size_t)M_DIM * K_DIM * 2 + (size_t)N_DIM * K_DIM * 2);

    // x rows (4096 blocks) + packed-w blocks (688 nblk x 8 kgroups = 5504)
    prep_kernel<<<M_DIM + 688 * 8, 256, 0, stream>>>(x, weight, xb, wb, s);

    gemm_kernel<<<dim3((N_DIM / 256) * (M_DIM / 256)), dim3(512), 0, stream>>>(
        xb, wb, s, scale, offset, bias, y);
}